// Round 9
// baseline (1128.588 us; speedup 1.0000x reference)
//
#include <hip/hip_runtime.h>
#include <hip/hip_bf16.h>
#include <hip/hip_fp16.h>

typedef _Float16 h2vec __attribute__((ext_vector_type(2)));
typedef _Float16 f16x4 __attribute__((ext_vector_type(4)));
typedef _Float16 f16x8 __attribute__((ext_vector_type(8)));
typedef float f32x4 __attribute__((ext_vector_type(4)));

static __device__ __forceinline__ float fast_sigmoid(float x) {
  return __builtin_amdgcn_rcpf(1.f + __expf(-x));
}
static __device__ __forceinline__ float fast_tanh(float x) {
  return 1.f - 2.f * __builtin_amdgcn_rcpf(__expf(2.f * x) + 1.f);
}

// ---------------------------------------------------------------------------
// f16-MFMA GEMM, fp32 out (head layers). C = act(A @ W^T + bias).
// MODE 1: relu(val + b0[n]); MODE 2: tanh(val + b0[n]).
// (Proven: 128x64 tile, XOR-swizzled LDS, 0 conflicts.)
// ---------------------------------------------------------------------------
template<int MODE>
__global__ __launch_bounds__(256) void gemm_mfma(
    const float* __restrict__ A, const float* __restrict__ W,
    const float* __restrict__ b0, const float* __restrict__ b1,
    float* __restrict__ C, int M, int N, int K) {
  __shared__ __align__(16) unsigned char As[128 * 128];
  __shared__ __align__(16) unsigned char Bs[64 * 128];
  const int tid = threadIdx.x;
  const int wave = tid >> 6, l = tid & 63;
  const int wm = wave >> 1, wn = wave & 1;
  const int m0 = blockIdx.x * 128, n0 = blockIdx.y * 64;
  const int lrow = l & 15, lq = l >> 4;

  f32x4 acc[4][2] = {};
  const int arow = tid >> 1, akc = (tid & 1) * 32;
  const int brow = tid >> 2, bkc = (tid & 3) * 16;

  for (int k0 = 0; k0 < K; k0 += 64) {
    {
      const float* src = A + (size_t)(m0 + arow) * K + k0 + akc;
#pragma unroll
      for (int u = 0; u < 4; ++u) {
        float4 v0 = *reinterpret_cast<const float4*>(src + u * 8);
        float4 v1 = *reinterpret_cast<const float4*>(src + u * 8 + 4);
        f16x8 h;
        h[0] = (_Float16)v0.x; h[1] = (_Float16)v0.y;
        h[2] = (_Float16)v0.z; h[3] = (_Float16)v0.w;
        h[4] = (_Float16)v1.x; h[5] = (_Float16)v1.y;
        h[6] = (_Float16)v1.z; h[7] = (_Float16)v1.w;
        const int kbyte = (akc + u * 8) * 2;
        *reinterpret_cast<f16x8*>(&As[arow * 128 + (kbyte ^ ((arow & 7) << 4))]) = h;
      }
    }
    {
      const float* src = W + (size_t)(n0 + brow) * K + k0 + bkc;
#pragma unroll
      for (int u = 0; u < 2; ++u) {
        float4 v0 = *reinterpret_cast<const float4*>(src + u * 8);
        float4 v1 = *reinterpret_cast<const float4*>(src + u * 8 + 4);
        f16x8 h;
        h[0] = (_Float16)v0.x; h[1] = (_Float16)v0.y;
        h[2] = (_Float16)v0.z; h[3] = (_Float16)v0.w;
        h[4] = (_Float16)v1.x; h[5] = (_Float16)v1.y;
        h[6] = (_Float16)v1.z; h[7] = (_Float16)v1.w;
        const int kbyte = (bkc + u * 8) * 2;
        *reinterpret_cast<f16x8*>(&Bs[brow * 128 + (kbyte ^ ((brow & 7) << 4))]) = h;
      }
    }
    __syncthreads();
#pragma unroll
    for (int kk = 0; kk < 64; kk += 32) {
      const int kbyte = (kk + lq * 8) * 2;
      f16x8 af[4], bf[2];
#pragma unroll
      for (int mt = 0; mt < 4; ++mt) {
        const int row = wm * 64 + mt * 16 + lrow;
        af[mt] = *reinterpret_cast<const f16x8*>(&As[row * 128 + (kbyte ^ ((row & 7) << 4))]);
      }
#pragma unroll
      for (int nt = 0; nt < 2; ++nt) {
        const int row = wn * 32 + nt * 16 + lrow;
        bf[nt] = *reinterpret_cast<const f16x8*>(&Bs[row * 128 + (kbyte ^ ((row & 7) << 4))]);
      }
#pragma unroll
      for (int mt = 0; mt < 4; ++mt)
#pragma unroll
        for (int nt = 0; nt < 2; ++nt)
          acc[mt][nt] = __builtin_amdgcn_mfma_f32_16x16x32_f16(af[mt], bf[nt], acc[mt][nt], 0, 0, 0);
    }
    __syncthreads();
  }

#pragma unroll
  for (int nt = 0; nt < 2; ++nt) {
    const int n = n0 + wn * 32 + nt * 16 + lrow;
    float bias = (MODE == 0) ? (b0[n] + b1[n]) : b0[n];
#pragma unroll
    for (int mt = 0; mt < 4; ++mt) {
#pragma unroll
      for (int r = 0; r < 4; ++r) {
        const int m = m0 + wm * 64 + mt * 16 + lq * 4 + r;
        float val = acc[mt][nt][r] + bias;
        if (MODE == 1) val = fmaxf(val, 0.f);
        if (MODE == 2) val = fast_tanh(val);
        C[(size_t)m * N + n] = val;
      }
    }
  }
}

// ---------------------------------------------------------------------------
// Fused fw+bw input-projection GEMM, f16 output (proven round 8).
// blockIdx.z selects direction. C_h = A @ W^T + bih + bhh (as __half).
// ---------------------------------------------------------------------------
__global__ __launch_bounds__(256) void gemm_proj_h(
    const float* __restrict__ A,
    const float* __restrict__ W0, const float* __restrict__ W1,
    const float* __restrict__ bi0, const float* __restrict__ bh0,
    const float* __restrict__ bi1, const float* __restrict__ bh1,
    __half* __restrict__ C0, __half* __restrict__ C1, int M, int N, int K) {
  const float* __restrict__ W  = blockIdx.z ? W1 : W0;
  const float* __restrict__ b0 = blockIdx.z ? bi1 : bi0;
  const float* __restrict__ b1 = blockIdx.z ? bh1 : bh0;
  __half* __restrict__ C = blockIdx.z ? C1 : C0;

  __shared__ __align__(16) unsigned char As[128 * 128];
  __shared__ __align__(16) unsigned char Bs[64 * 128];
  const int tid = threadIdx.x;
  const int wave = tid >> 6, l = tid & 63;
  const int wm = wave >> 1, wn = wave & 1;
  const int m0 = blockIdx.x * 128, n0 = blockIdx.y * 64;
  const int lrow = l & 15, lq = l >> 4;

  f32x4 acc[4][2] = {};
  const int arow = tid >> 1, akc = (tid & 1) * 32;
  const int brow = tid >> 2, bkc = (tid & 3) * 16;

  for (int k0 = 0; k0 < K; k0 += 64) {
    {
      const float* src = A + (size_t)(m0 + arow) * K + k0 + akc;
#pragma unroll
      for (int u = 0; u < 4; ++u) {
        float4 v0 = *reinterpret_cast<const float4*>(src + u * 8);
        float4 v1 = *reinterpret_cast<const float4*>(src + u * 8 + 4);
        f16x8 h;
        h[0] = (_Float16)v0.x; h[1] = (_Float16)v0.y;
        h[2] = (_Float16)v0.z; h[3] = (_Float16)v0.w;
        h[4] = (_Float16)v1.x; h[5] = (_Float16)v1.y;
        h[6] = (_Float16)v1.z; h[7] = (_Float16)v1.w;
        const int kbyte = (akc + u * 8) * 2;
        *reinterpret_cast<f16x8*>(&As[arow * 128 + (kbyte ^ ((arow & 7) << 4))]) = h;
      }
    }
    {
      const float* src = W + (size_t)(n0 + brow) * K + k0 + bkc;
#pragma unroll
      for (int u = 0; u < 2; ++u) {
        float4 v0 = *reinterpret_cast<const float4*>(src + u * 8);
        float4 v1 = *reinterpret_cast<const float4*>(src + u * 8 + 4);
        f16x8 h;
        h[0] = (_Float16)v0.x; h[1] = (_Float16)v0.y;
        h[2] = (_Float16)v0.z; h[3] = (_Float16)v0.w;
        h[4] = (_Float16)v1.x; h[5] = (_Float16)v1.y;
        h[6] = (_Float16)v1.z; h[7] = (_Float16)v1.w;
        const int kbyte = (bkc + u * 8) * 2;
        *reinterpret_cast<f16x8*>(&Bs[brow * 128 + (kbyte ^ ((brow & 7) << 4))]) = h;
      }
    }
    __syncthreads();
#pragma unroll
    for (int kk = 0; kk < 64; kk += 32) {
      const int kbyte = (kk + lq * 8) * 2;
      f16x8 af[4], bf[2];
#pragma unroll
      for (int mt = 0; mt < 4; ++mt) {
        const int row = wm * 64 + mt * 16 + lrow;
        af[mt] = *reinterpret_cast<const f16x8*>(&As[row * 128 + (kbyte ^ ((row & 7) << 4))]);
      }
#pragma unroll
      for (int nt = 0; nt < 2; ++nt) {
        const int row = wn * 32 + nt * 16 + lrow;
        bf[nt] = *reinterpret_cast<const f16x8*>(&Bs[row * 128 + (kbyte ^ ((row & 7) << 4))]);
      }
#pragma unroll
      for (int mt = 0; mt < 4; ++mt)
#pragma unroll
        for (int nt = 0; nt < 2; ++nt)
          acc[mt][nt] = __builtin_amdgcn_mfma_f32_16x16x32_f16(af[mt], bf[nt], acc[mt][nt], 0, 0, 0);
    }
    __syncthreads();
  }

#pragma unroll
  for (int nt = 0; nt < 2; ++nt) {
    const int n = n0 + wn * 32 + nt * 16 + lrow;
    const float bias = b0[n] + b1[n];
#pragma unroll
    for (int mt = 0; mt < 4; ++mt) {
#pragma unroll
      for (int r = 0; r < 4; ++r) {
        const int m = m0 + wm * 64 + mt * 16 + lq * 4 + r;
        C[(size_t)m * N + n] = __float2half_rn(acc[mt][nt][r] + bias);
      }
    }
  }
}

// ---------------------------------------------------------------------------
// LSTM recurrence, v7 = v5-mfma with its three failure modes fixed:
//  (1) LDS rows 256B + XOR swizzle (byte ^= (col&7)<<4): B-frag ds_read_b128
//      2-way max (free) instead of 16-way conflicted.
//  (2) raw s_barrier with lgkmcnt(0)-only wait: xg loads in flight across
//      barriers (no per-step vmcnt(0) drain).
//  (3) xg in f16 (8B/lane/step), depth-2 register rotation.
// Grid (4 batch-tiles, 2 dirs) = 8 blocks, 512 thr = 8 waves. Per step:
// G[16,512] = Whh[512,128] @ h[16,128]^T via mfma_f32_16x16x32_f16
// (16 MFMA/wave). D col=batch, row q*4+r -> unit w*16+q*4+r; gates of one
// (batch,unit) in one lane -> activation fully in-register, c in VGPRs.
// One barrier/step (double-buffered h).
// ---------------------------------------------------------------------------
__global__ __launch_bounds__(512, 1) void lstm_mfma2(
    const __half* __restrict__ xg_f, const __half* __restrict__ xg_b,
    const float* __restrict__ Whh_f, const float* __restrict__ Whh_b,
    float* __restrict__ out) {
  const int bt = blockIdx.x;       // batches bt*16 .. +15
  const int dir = blockIdx.y;
  const int tid = threadIdx.x;
  const int w = tid >> 6;          // wave 0..7 -> units w*16 .. +15
  const int l = tid & 63;
  const int col = l & 15;          // batch-within-tile
  const int q = l >> 4;

  const __half* __restrict__ xg = dir ? xg_b : xg_f;
  const float* __restrict__ Whh = dir ? Whh_b : Whh_f;

  __shared__ __align__(16) unsigned char h_lds[2][16 * 256];  // row=batch, 256B

  // A-frags of Whh (VGPR-resident): wave w, gates (g*8+w)*16 + (l&15)
  f16x8 a[4][4];
#pragma unroll
  for (int g = 0; g < 4; ++g) {
    const int gate = (g * 8 + w) * 16 + col;
#pragma unroll
    for (int kf = 0; kf < 4; ++kf) {
      const float* p = Whh + (size_t)gate * 128 + kf * 32 + q * 8;
      float4 v0 = *reinterpret_cast<const float4*>(p);
      float4 v1 = *reinterpret_cast<const float4*>(p + 4);
      f16x8 av;
      av[0] = (_Float16)v0.x; av[1] = (_Float16)v0.y;
      av[2] = (_Float16)v0.z; av[3] = (_Float16)v0.w;
      av[4] = (_Float16)v1.x; av[5] = (_Float16)v1.y;
      av[6] = (_Float16)v1.z; av[7] = (_Float16)v1.w;
      a[g][kf] = av;
    }
  }

  for (int i = tid; i < (int)(sizeof(h_lds) / 4); i += 512)
    reinterpret_cast<unsigned int*>(h_lds)[i] = 0u;
  f32x4 c4 = {0.f, 0.f, 0.f, 0.f};
  __syncthreads();

  const int tt0 = dir ? 511 : 0;
  const int stp = dir ? -1 : 1;
  const int b_glob = bt * 16 + col;
  const size_t xbase = (size_t)b_glob * 512 * 512;  // xg[b][t][512] (f16)
  const int goff = w * 16 + q * 4;                  // unit base for this lane
  const int swz = (col & 7) << 4;

  struct XReg { f16x4 v[4]; };
  XReg xva, xvb;
#pragma unroll
  for (int g = 0; g < 4; ++g) {
    xva.v[g] = *reinterpret_cast<const f16x4*>(xg + xbase + (size_t)tt0 * 512 + g * 128 + goff);
    xvb.v[g] = *reinterpret_cast<const f16x4*>(xg + xbase + (size_t)(tt0 + stp) * 512 + g * 128 + goff);
  }

  auto step = [&](int t, unsigned char* rbuf, unsigned char* wbuf, XReg& xcur)
      __attribute__((always_inline)) {
    const int tt = tt0 + stp * t;

    // B-frags: h[col][kf*32 + q*8 ..+7], swizzled (2-way max = free)
    f16x8 bf[4];
#pragma unroll
    for (int kf = 0; kf < 4; ++kf) {
      const int byte = ((kf * 32 + q * 8) * 2) ^ swz;
      bf[kf] = *reinterpret_cast<const f16x8*>(&rbuf[col * 256 + byte]);
    }

    f32x4 acc[4] = {{0.f,0.f,0.f,0.f},{0.f,0.f,0.f,0.f},
                    {0.f,0.f,0.f,0.f},{0.f,0.f,0.f,0.f}};
#pragma unroll
    for (int kf = 0; kf < 4; ++kf) {
#pragma unroll
      for (int g = 0; g < 4; ++g)
        acc[g] = __builtin_amdgcn_mfma_f32_16x16x32_f16(a[g][kf], bf[kf], acc[g], 0, 0, 0);
    }

    // gates + state (in-register); element r -> unit goff+r, batch col
    f16x4 hpack;
    float hout[4];
#pragma unroll
    for (int r = 0; r < 4; ++r) {
      const float gi = fast_sigmoid(acc[0][r] + (float)xcur.v[0][r]);
      const float gf = fast_sigmoid(acc[1][r] + (float)xcur.v[1][r]);
      const float gg = fast_tanh(acc[2][r] + (float)xcur.v[2][r]);
      const float go = fast_sigmoid(acc[3][r] + (float)xcur.v[3][r]);
      c4[r] = gf * c4[r] + gi * gg;
      const float h = go * fast_tanh(c4[r]);
      hpack[r] = (_Float16)h;
      hout[r] = h;
    }

    // prefetch xg for t+2 into the same registers (in flight across barriers)
    {
      const int t2 = t + 2;
      const int tt2 = (t2 < 512) ? (tt0 + stp * t2) : tt0;
#pragma unroll
      for (int g = 0; g < 4; ++g)
        xcur.v[g] = *reinterpret_cast<const f16x4*>(
            xg + xbase + (size_t)tt2 * 512 + g * 128 + goff);
    }

    // h -> next LDS buffer (8B write, swizzle-slot-contained)
    *reinterpret_cast<f16x4*>(&wbuf[col * 256 + ((goff * 2) ^ swz)]) = hpack;

    // h -> global out (fire-and-forget store)
    *reinterpret_cast<float4*>(out + ((size_t)b_glob * 512 + tt) * 256 + dir * 128 + goff)
        = make_float4(hout[0], hout[1], hout[2], hout[3]);

    asm volatile("s_waitcnt lgkmcnt(0)" ::: "memory");
    __builtin_amdgcn_s_barrier();
    asm volatile("" ::: "memory");
  };

  for (int it = 0; it < 256; ++it) {
    step(2 * it,     h_lds[0], h_lds[1], xva);
    step(2 * it + 1, h_lds[1], h_lds[0], xvb);
  }
}

// ---------------------------------------------------------------------------
// Launcher
// ---------------------------------------------------------------------------
extern "C" void kernel_launch(void* const* d_in, const int* in_sizes, int n_in,
                              void* d_out, int out_size, void* d_ws, size_t ws_size,
                              hipStream_t stream) {
  (void)in_sizes; (void)n_in; (void)out_size; (void)ws_size;

  const float* x     = (const float*)d_in[0];
  const float* Wih00 = (const float*)d_in[1];
  const float* Whh00 = (const float*)d_in[2];
  const float* bih00 = (const float*)d_in[3];
  const float* bhh00 = (const float*)d_in[4];
  const float* Wih01 = (const float*)d_in[5];
  const float* Whh01 = (const float*)d_in[6];
  const float* bih01 = (const float*)d_in[7];
  const float* bhh01 = (const float*)d_in[8];
  const float* Wih10 = (const float*)d_in[9];
  const float* Whh10 = (const float*)d_in[10];
  const float* bih10 = (const float*)d_in[11];
  const float* bhh10 = (const float*)d_in[12];
  const float* Wih11 = (const float*)d_in[13];
  const float* Whh11 = (const float*)d_in[14];
  const float* bih11 = (const float*)d_in[15];
  const float* bhh11 = (const float*)d_in[16];
  const float* W1 = (const float*)d_in[17];
  const float* b1 = (const float*)d_in[18];
  const float* W2 = (const float*)d_in[19];
  const float* b2 = (const float*)d_in[20];
  float* out = (float*)d_out;

  char* ws = (char*)d_ws;
  __half* xgh_f = (__half*)ws;                          // 32 MB [B,T,512] f16
  __half* xgh_b = (__half*)(ws + ((size_t)32 << 20));   // 32 MB
  float*  buf   = (float*)(ws + ((size_t)64 << 20));    // 32 MB [B,T,256] f32
  float*  tmp   = (float*)(ws + ((size_t)96 << 20));    // 32 MB head intermediate

  const int M = 64 * 512;  // 32768 rows

  // ---- layer 0 ----
  gemm_proj_h<<<dim3(M / 128, 8, 2), 256, 0, stream>>>(
      x, Wih00, Wih01, bih00, bhh00, bih01, bhh01, xgh_f, xgh_b, M, 512, 64);
  lstm_mfma2<<<dim3(4, 2), 512, 0, stream>>>(xgh_f, xgh_b, Whh00, Whh01, buf);

  // ---- layer 1 ----
  gemm_proj_h<<<dim3(M / 128, 8, 2), 256, 0, stream>>>(
      buf, Wih10, Wih11, bih10, bhh10, bih11, bhh11, xgh_f, xgh_b, M, 512, 256);
  lstm_mfma2<<<dim3(4, 2), 512, 0, stream>>>(xgh_f, xgh_b, Whh10, Whh11, buf);

  // ---- head ----
  gemm_mfma<1><<<dim3(M / 128, 4), 256, 0, stream>>>(
      buf, W1, b1, nullptr, tmp, M, 256, 256);
  gemm_mfma<2><<<dim3(M / 128, 1), 256, 0, stream>>>(
      tmp, W2, b2, nullptr, out, M, 64, 256);
}

// Round 10
// 629.931 us; speedup vs baseline: 1.7916x; 1.7916x over previous
//
#include <hip/hip_runtime.h>
#include <hip/hip_bf16.h>
#include <hip/hip_fp16.h>

typedef _Float16 h2vec __attribute__((ext_vector_type(2)));
typedef _Float16 f16x8 __attribute__((ext_vector_type(8)));
typedef float f32x4 __attribute__((ext_vector_type(4)));

static __device__ __forceinline__ float fast_sigmoid(float x) {
  return __builtin_amdgcn_rcpf(1.f + __expf(-x));
}
static __device__ __forceinline__ float fast_tanh(float x) {
  return 1.f - 2.f * __builtin_amdgcn_rcpf(__expf(2.f * x) + 1.f);
}
static __device__ __forceinline__ float fdot2u(unsigned int a, unsigned int b, float c) {
#if __has_builtin(__builtin_amdgcn_fdot2)
  return __builtin_amdgcn_fdot2(__builtin_bit_cast(h2vec, a),
                                __builtin_bit_cast(h2vec, b), c, false);
#else
  h2vec av = __builtin_bit_cast(h2vec, a);
  h2vec bv = __builtin_bit_cast(h2vec, b);
  return c + (float)av[0] * (float)bv[0] + (float)av[1] * (float)bv[1];
#endif
}
template<int CTRL>
static __device__ __forceinline__ float dpp_add(float v) {
  int x = __builtin_bit_cast(int, v);
  int y = __builtin_amdgcn_update_dpp(0, x, CTRL, 0xF, 0xF, true);
  return v + __builtin_bit_cast(float, y);
}
template<int CTRL>
static __device__ __forceinline__ float dpp_mov(float v) {
  int x = __builtin_bit_cast(int, v);
  int y = __builtin_amdgcn_update_dpp(0, x, CTRL, 0xF, 0xF, true);
  return __builtin_bit_cast(float, y);
}

// ---------------------------------------------------------------------------
// A-tile staging helper: f32 or f16 source -> f16 swizzled LDS rows (128B).
// Thread covers 32 columns of one row starting at akc.
// ---------------------------------------------------------------------------
template<typename AT>
static __device__ __forceinline__ void stage_row32(
    const AT* __restrict__ src, unsigned char* __restrict__ dst,
    int row, int kc /*column start*/) {
#pragma unroll
  for (int u = 0; u < 4; ++u) {
    f16x8 h;
    if constexpr (sizeof(AT) == 4) {
      float4 v0 = *reinterpret_cast<const float4*>((const float*)src + u * 8);
      float4 v1 = *reinterpret_cast<const float4*>((const float*)src + u * 8 + 4);
      h[0] = (_Float16)v0.x; h[1] = (_Float16)v0.y;
      h[2] = (_Float16)v0.z; h[3] = (_Float16)v0.w;
      h[4] = (_Float16)v1.x; h[5] = (_Float16)v1.y;
      h[6] = (_Float16)v1.z; h[7] = (_Float16)v1.w;
    } else {
      h = *reinterpret_cast<const f16x8*>((const __half*)src + u * 8);
    }
    const int kbyte = (kc + u * 8) * 2;
    *reinterpret_cast<f16x8*>(&dst[row * 128 + (kbyte ^ ((row & 7) << 4))]) = h;
  }
}

// ---------------------------------------------------------------------------
// f16-MFMA GEMM. C = act(A @ W^T + bias). A: float or __half. C: float or
// __half. W,b: float. Tile 128x64x64, 4 waves, swizzled LDS (0 conflicts).
// MODE 0: +b0+b1; MODE 1: relu(+b0); MODE 2: tanh(+b0).
// ---------------------------------------------------------------------------
template<typename AT, typename OT, int MODE>
__global__ __launch_bounds__(256) void gemm_mfma2(
    const AT* __restrict__ A, const float* __restrict__ W,
    const float* __restrict__ b0, const float* __restrict__ b1,
    OT* __restrict__ C, int M, int N, int K) {
  __shared__ __align__(16) unsigned char As[128 * 128];
  __shared__ __align__(16) unsigned char Bs[64 * 128];
  const int tid = threadIdx.x;
  const int wave = tid >> 6, l = tid & 63;
  const int wm = wave >> 1, wn = wave & 1;
  const int m0 = blockIdx.x * 128, n0 = blockIdx.y * 64;
  const int lrow = l & 15, lq = l >> 4;

  f32x4 acc[4][2] = {};
  const int arow = tid >> 1, akc = (tid & 1) * 32;
  const int brow = tid >> 2, bkc = (tid & 3) * 16;

  for (int k0 = 0; k0 < K; k0 += 64) {
    stage_row32<AT>(A + (size_t)(m0 + arow) * K + k0 + akc, As, arow, akc);
    {
      const float* src = W + (size_t)(n0 + brow) * K + k0 + bkc;
#pragma unroll
      for (int u = 0; u < 2; ++u) {
        float4 v0 = *reinterpret_cast<const float4*>(src + u * 8);
        float4 v1 = *reinterpret_cast<const float4*>(src + u * 8 + 4);
        f16x8 h;
        h[0] = (_Float16)v0.x; h[1] = (_Float16)v0.y;
        h[2] = (_Float16)v0.z; h[3] = (_Float16)v0.w;
        h[4] = (_Float16)v1.x; h[5] = (_Float16)v1.y;
        h[6] = (_Float16)v1.z; h[7] = (_Float16)v1.w;
        const int kbyte = (bkc + u * 8) * 2;
        *reinterpret_cast<f16x8*>(&Bs[brow * 128 + (kbyte ^ ((brow & 7) << 4))]) = h;
      }
    }
    __syncthreads();
#pragma unroll
    for (int kk = 0; kk < 64; kk += 32) {
      const int kbyte = (kk + lq * 8) * 2;
      f16x8 af[4], bf[2];
#pragma unroll
      for (int mt = 0; mt < 4; ++mt) {
        const int row = wm * 64 + mt * 16 + lrow;
        af[mt] = *reinterpret_cast<const f16x8*>(&As[row * 128 + (kbyte ^ ((row & 7) << 4))]);
      }
#pragma unroll
      for (int nt = 0; nt < 2; ++nt) {
        const int row = wn * 32 + nt * 16 + lrow;
        bf[nt] = *reinterpret_cast<const f16x8*>(&Bs[row * 128 + (kbyte ^ ((row & 7) << 4))]);
      }
#pragma unroll
      for (int mt = 0; mt < 4; ++mt)
#pragma unroll
        for (int nt = 0; nt < 2; ++nt)
          acc[mt][nt] = __builtin_amdgcn_mfma_f32_16x16x32_f16(af[mt], bf[nt], acc[mt][nt], 0, 0, 0);
    }
    __syncthreads();
  }

#pragma unroll
  for (int nt = 0; nt < 2; ++nt) {
    const int n = n0 + wn * 32 + nt * 16 + lrow;
    float bias = (MODE == 0) ? (b0[n] + b1[n]) : b0[n];
#pragma unroll
    for (int mt = 0; mt < 4; ++mt) {
#pragma unroll
      for (int r = 0; r < 4; ++r) {
        const int m = m0 + wm * 64 + mt * 16 + lq * 4 + r;
        float val = acc[mt][nt][r] + bias;
        if (MODE == 1) val = fmaxf(val, 0.f);
        if (MODE == 2) val = fast_tanh(val);
        if constexpr (sizeof(OT) == 2)
          C[(size_t)m * N + n] = __float2half_rn(val);
        else
          C[(size_t)m * N + n] = val;
      }
    }
  }
}

// ---------------------------------------------------------------------------
// Fused fw+bw input-projection GEMM, f16 output. blockIdx.z selects
// direction. C_h = A @ W^T + bih + bhh (as __half). A: float or __half.
// ---------------------------------------------------------------------------
template<typename AT>
__global__ __launch_bounds__(256) void gemm_proj_h(
    const AT* __restrict__ A,
    const float* __restrict__ W0, const float* __restrict__ W1,
    const float* __restrict__ bi0, const float* __restrict__ bh0,
    const float* __restrict__ bi1, const float* __restrict__ bh1,
    __half* __restrict__ C0, __half* __restrict__ C1, int M, int N, int K) {
  const float* __restrict__ W  = blockIdx.z ? W1 : W0;
  const float* __restrict__ b0 = blockIdx.z ? bi1 : bi0;
  const float* __restrict__ b1 = blockIdx.z ? bh1 : bh0;
  __half* __restrict__ C = blockIdx.z ? C1 : C0;

  __shared__ __align__(16) unsigned char As[128 * 128];
  __shared__ __align__(16) unsigned char Bs[64 * 128];
  const int tid = threadIdx.x;
  const int wave = tid >> 6, l = tid & 63;
  const int wm = wave >> 1, wn = wave & 1;
  const int m0 = blockIdx.x * 128, n0 = blockIdx.y * 64;
  const int lrow = l & 15, lq = l >> 4;

  f32x4 acc[4][2] = {};
  const int arow = tid >> 1, akc = (tid & 1) * 32;
  const int brow = tid >> 2, bkc = (tid & 3) * 16;

  for (int k0 = 0; k0 < K; k0 += 64) {
    stage_row32<AT>(A + (size_t)(m0 + arow) * K + k0 + akc, As, arow, akc);
    {
      const float* src = W + (size_t)(n0 + brow) * K + k0 + bkc;
#pragma unroll
      for (int u = 0; u < 2; ++u) {
        float4 v0 = *reinterpret_cast<const float4*>(src + u * 8);
        float4 v1 = *reinterpret_cast<const float4*>(src + u * 8 + 4);
        f16x8 h;
        h[0] = (_Float16)v0.x; h[1] = (_Float16)v0.y;
        h[2] = (_Float16)v0.z; h[3] = (_Float16)v0.w;
        h[4] = (_Float16)v1.x; h[5] = (_Float16)v1.y;
        h[6] = (_Float16)v1.z; h[7] = (_Float16)v1.w;
        const int kbyte = (bkc + u * 8) * 2;
        *reinterpret_cast<f16x8*>(&Bs[brow * 128 + (kbyte ^ ((brow & 7) << 4))]) = h;
      }
    }
    __syncthreads();
#pragma unroll
    for (int kk = 0; kk < 64; kk += 32) {
      const int kbyte = (kk + lq * 8) * 2;
      f16x8 af[4], bf[2];
#pragma unroll
      for (int mt = 0; mt < 4; ++mt) {
        const int row = wm * 64 + mt * 16 + lrow;
        af[mt] = *reinterpret_cast<const f16x8*>(&As[row * 128 + (kbyte ^ ((row & 7) << 4))]);
      }
#pragma unroll
      for (int nt = 0; nt < 2; ++nt) {
        const int row = wn * 32 + nt * 16 + lrow;
        bf[nt] = *reinterpret_cast<const f16x8*>(&Bs[row * 128 + (kbyte ^ ((row & 7) << 4))]);
      }
#pragma unroll
      for (int mt = 0; mt < 4; ++mt)
#pragma unroll
        for (int nt = 0; nt < 2; ++nt)
          acc[mt][nt] = __builtin_amdgcn_mfma_f32_16x16x32_f16(af[mt], bf[nt], acc[mt][nt], 0, 0, 0);
    }
    __syncthreads();
  }

#pragma unroll
  for (int nt = 0; nt < 2; ++nt) {
    const int n = n0 + wn * 32 + nt * 16 + lrow;
    const float bias = b0[n] + b1[n];
#pragma unroll
    for (int mt = 0; mt < 4; ++mt) {
#pragma unroll
      for (int r = 0; r < 4; ++r) {
        const int m = m0 + wm * 64 + mt * 16 + lq * 4 + r;
        C[(size_t)m * N + n] = __float2half_rn(acc[mt][nt][r] + bias);
      }
    }
  }
}

// ---------------------------------------------------------------------------
// LSTM recurrence (v5 structure — proven 283 us/layer), f16 xg + f16 out.
// One 512-thread block per (batch, direction) = 128 blocks. Lane
// (j = tid>>2 unit, kq = tid&3 k-quarter): 4 gate-rows x quarter-k = 64
// dot2/lane. Quad DPP allreduce, lane kq activates gate kq (tanh via
// 2*sigmoid(2x)-1), quad_perm broadcasts. h as f16 in LDS, double-buffered.
// Raw s_barrier with lgkmcnt(0)-only wait (xg loads fly across barriers);
// xg prefetch depth 2 via xva/xvb rotation.
// ---------------------------------------------------------------------------
__global__ __launch_bounds__(512, 2) void lstm_seq5h(
    const __half* __restrict__ xg_f, const __half* __restrict__ xg_b,
    const float* __restrict__ Whh_f, const float* __restrict__ Whh_b,
    __half* __restrict__ out) {
  const int b = blockIdx.x;
  const int dir = blockIdx.y;
  const int tid = threadIdx.x;
  const int j = tid >> 2;   // unit 0..127
  const int kq = tid & 3;   // k quarter
  const __half* __restrict__ xg = dir ? xg_b : xg_f;
  const float* __restrict__ Whh = dir ? Whh_b : Whh_f;

  __shared__ unsigned int hbuf[2][64];  // h as f16 pairs, double-buffered

  // Weights: w[g][kk] = f16x2 of row (g*128+j), k = kq*32 + 2*kk, +1
  unsigned int w[4][16];
#pragma unroll
  for (int g = 0; g < 4; ++g) {
    const float4* wr = reinterpret_cast<const float4*>(
        Whh + (size_t)(g * 128 + j) * 128 + kq * 32);
#pragma unroll
    for (int q = 0; q < 8; ++q) {
      float4 v = wr[q];
      __half2 p0 = __floats2half2_rn(v.x, v.y);
      __half2 p1 = __floats2half2_rn(v.z, v.w);
      w[g][2 * q]     = __builtin_bit_cast(unsigned int, p0);
      w[g][2 * q + 1] = __builtin_bit_cast(unsigned int, p1);
    }
  }

  if (tid < 128) hbuf[tid >> 6][tid & 63] = 0u;
  float c = 0.f;
  __syncthreads();

  const int tt0 = dir ? 511 : 0;
  const int stp = dir ? -1 : 1;
  const size_t base = (size_t)b * 512 * 512;
  const int xidx = kq * 128 + j;  // gate kq of unit j

  unsigned short xva = __builtin_bit_cast(unsigned short, xg[base + (size_t)tt0 * 512 + xidx]);
  unsigned short xvb = __builtin_bit_cast(unsigned short, xg[base + (size_t)(tt0 + stp) * 512 + xidx]);

  auto step = [&](int t, unsigned int* rbuf, unsigned int* wbuf, unsigned short& xcur)
      __attribute__((always_inline)) {
    const int tt = tt0 + stp * t;

    // my h quarter: 4 x ds_read_b128, broadcast among 16 lanes each
    const uint4* hc = reinterpret_cast<const uint4*>(&rbuf[kq * 16]);
    uint4 q0 = hc[0], q1 = hc[1], q2 = hc[2], q3 = hc[3];
    unsigned int ha[16];
    ha[0] = q0.x; ha[1] = q0.y; ha[2] = q0.z; ha[3] = q0.w;
    ha[4] = q1.x; ha[5] = q1.y; ha[6] = q1.z; ha[7] = q1.w;
    ha[8] = q2.x; ha[9] = q2.y; ha[10] = q2.z; ha[11] = q2.w;
    ha[12] = q3.x; ha[13] = q3.y; ha[14] = q3.z; ha[15] = q3.w;

    float acc[4] = {0.f, 0.f, 0.f, 0.f};
#pragma unroll
    for (int kk = 0; kk < 16; ++kk) {
#pragma unroll
      for (int g = 0; g < 4; ++g)
        acc[g] = fdot2u(w[g][kk], ha[kk], acc[g]);
    }

    // quad allreduce
#pragma unroll
    for (int g = 0; g < 4; ++g) {
      float a = acc[g];
      a = dpp_add<0xB1>(a);  // xor 1
      a = dpp_add<0x4E>(a);  // xor 2
      acc[g] = a;
    }

    // lane kq activates gate kq
    float a = acc[0];
    a = (kq == 1) ? acc[1] : a;
    a = (kq == 2) ? acc[2] : a;
    a = (kq == 3) ? acc[3] : a;
    a += (float)__builtin_bit_cast(_Float16, xcur);

    // prefetch xg for t+2 (stays in flight across raw barriers)
    {
      const int t2 = t + 2;
      const int tt2 = (t2 < 512) ? (tt0 + stp * t2) : tt0;
      xcur = __builtin_bit_cast(unsigned short, xg[base + (size_t)tt2 * 512 + xidx]);
    }

    const float xs = (kq == 2) ? 2.f * a : a;
    const float y = fast_sigmoid(xs);
    const float act = (kq == 2) ? 2.f * y - 1.f : y;

    const float gi = dpp_mov<0x00>(act);
    const float gf = dpp_mov<0x55>(act);
    const float gg = dpp_mov<0xAA>(act);
    const float go = dpp_mov<0xFF>(act);

    c = gf * c + gi * gg;
    const float h = go * (2.f * fast_sigmoid(2.f * c) - 1.f);

    if (kq == 0) {  // h[j] -> next step's buffer (f16)
      unsigned short us = __builtin_bit_cast(unsigned short, (_Float16)h);
      reinterpret_cast<unsigned short*>(wbuf)[j] = us;
    }
    if (kq == 1) {  // h[j] -> global out (f16)
      out[((size_t)b * 512 + tt) * 256 + dir * 128 + j] = __float2half_rn(h);
    }

    asm volatile("s_waitcnt lgkmcnt(0)" ::: "memory");
    __builtin_amdgcn_s_barrier();
    asm volatile("" ::: "memory");
  };

  for (int it = 0; it < 256; ++it) {
    step(2 * it,     hbuf[0], hbuf[1], xva);
    step(2 * it + 1, hbuf[1], hbuf[0], xvb);
  }
}

// ---------------------------------------------------------------------------
// Launcher
// ---------------------------------------------------------------------------
extern "C" void kernel_launch(void* const* d_in, const int* in_sizes, int n_in,
                              void* d_out, int out_size, void* d_ws, size_t ws_size,
                              hipStream_t stream) {
  (void)in_sizes; (void)n_in; (void)out_size; (void)ws_size;

  const float* x     = (const float*)d_in[0];
  const float* Wih00 = (const float*)d_in[1];
  const float* Whh00 = (const float*)d_in[2];
  const float* bih00 = (const float*)d_in[3];
  const float* bhh00 = (const float*)d_in[4];
  const float* Wih01 = (const float*)d_in[5];
  const float* Whh01 = (const float*)d_in[6];
  const float* bih01 = (const float*)d_in[7];
  const float* bhh01 = (const float*)d_in[8];
  const float* Wih10 = (const float*)d_in[9];
  const float* Whh10 = (const float*)d_in[10];
  const float* bih10 = (const float*)d_in[11];
  const float* bhh10 = (const float*)d_in[12];
  const float* Wih11 = (const float*)d_in[13];
  const float* Whh11 = (const float*)d_in[14];
  const float* bih11 = (const float*)d_in[15];
  const float* bhh11 = (const float*)d_in[16];
  const float* W1 = (const float*)d_in[17];
  const float* b1 = (const float*)d_in[18];
  const float* W2 = (const float*)d_in[19];
  const float* b2 = (const float*)d_in[20];
  float* out = (float*)d_out;

  char* ws = (char*)d_ws;
  __half* xgh_f = (__half*)ws;                          // 32 MB [B,T,512] f16
  __half* xgh_b = (__half*)(ws + ((size_t)32 << 20));   // 32 MB
  __half* bufh  = (__half*)(ws + ((size_t)64 << 20));   // 16 MB [B,T,256] f16
  __half* tmph  = (__half*)(ws + ((size_t)80 << 20));   // 16 MB head intermediate

  const int M = 64 * 512;  // 32768 rows

  // ---- layer 0 ----
  gemm_proj_h<float><<<dim3(M / 128, 8, 2), 256, 0, stream>>>(
      x, Wih00, Wih01, bih00, bhh00, bih01, bhh01, xgh_f, xgh_b, M, 512, 64);
  lstm_seq5h<<<dim3(64, 2), 512, 0, stream>>>(xgh_f, xgh_b, Whh00, Whh01, bufh);

  // ---- layer 1 ----
  gemm_proj_h<__half><<<dim3(M / 128, 8, 2), 256, 0, stream>>>(
      bufh, Wih10, Wih11, bih10, bhh10, bih11, bhh11, xgh_f, xgh_b, M, 512, 256);
  lstm_seq5h<<<dim3(64, 2), 512, 0, stream>>>(xgh_f, xgh_b, Whh10, Whh11, bufh);

  // ---- head ----
  gemm_mfma2<__half, __half, 1><<<dim3(M / 128, 4), 256, 0, stream>>>(
      bufh, W1, b1, nullptr, tmph, M, 256, 256);
  gemm_mfma2<__half, float, 2><<<dim3(M / 128, 1), 256, 0, stream>>>(
      tmph, W2, b2, nullptr, out, M, 64, 256);
}